// Round 5
// baseline (329.041 us; speedup 1.0000x reference)
//
#include <hip/hip_runtime.h>
#include <hip/hip_cooperative_groups.h>
#include <math.h>

namespace cg = cooperative_groups;

#define D_MODEL 4096
#define D_INNER 8192
#define D_STATE 64
#define PROJ_OUT (2 * D_INNER + 2 * D_STATE + 1)  // 16513

typedef float f32x4 __attribute__((ext_vector_type(4)));

// ws layout (floats):
#define NSEG1 4
#define PP1_STRIDE 16516                 // PROJ_OUT padded to x4
#define G_OFF (NSEG1 * PP1_STRIDE)       // 66064
#define NSEG3 8
#define OP_OFF (G_OFF + D_INNER)         // 74256, out_part: 8 x 4096

#define NU1 (2065 * NSEG1)   // 8260 phase-1 units (4 row-pairs x 1 col-seg each)
#define NU2 512              // phase-2 units (16 d-rows each)
#define NU3 (512 * NSEG3)    // 4096 phase-3 units
#define NU4 16               // phase-4 fold units (256 outs each)

// ===========================================================================
// Phase bodies as inline functions, shared by the fused (cooperative) kernel
// and the 4-kernel fallback so both paths are bitwise identical.
// ===========================================================================
__device__ __forceinline__ void phase1_body(
    int u, int wave, int lane,
    const float* __restrict__ W_in, const float* __restrict__ x,
    float* __restrict__ pp) {
    const int seg  = u & (NSEG1 - 1);
    const int pair = (u >> 2) * 4 + wave;
    const int row0 = pair * 2;
    if (row0 >= PROJ_OUT) return;
    const int row1 = row0 + 1;
    const bool has1 = (row1 < PROJ_OUT);
    const int k0 = seg * (D_MODEL / NSEG1);
    const float* Wr0 = W_in + (size_t)row0 * D_MODEL + k0;
    const float* Wr1 = has1 ? (Wr0 + D_MODEL) : Wr0;
    const float* xp  = x + k0;

    float acc0 = 0.f, acc1 = 0.f;
    #pragma unroll
    for (int k = lane * 4; k < D_MODEL / NSEG1; k += 64 * 4) {
        f32x4 xv = *reinterpret_cast<const f32x4*>(xp + k);
        f32x4 w0 = __builtin_nontemporal_load(reinterpret_cast<const f32x4*>(Wr0 + k));
        f32x4 w1 = __builtin_nontemporal_load(reinterpret_cast<const f32x4*>(Wr1 + k));
        acc0 += w0.x * xv.x + w0.y * xv.y + w0.z * xv.z + w0.w * xv.w;
        acc1 += w1.x * xv.x + w1.y * xv.y + w1.z * xv.z + w1.w * xv.w;
    }
    #pragma unroll
    for (int off = 32; off; off >>= 1) {
        acc0 += __shfl_down(acc0, off, 64);
        acc1 += __shfl_down(acc1, off, 64);
    }
    if (lane == 0) {
        pp[seg * PP1_STRIDE + row0] = acc0;
        if (has1) pp[seg * PP1_STRIDE + row1] = acc1;
    }
}

__device__ __forceinline__ void phase2_body(
    int u, int wave, int lane,
    const float* __restrict__ pp, const float* __restrict__ state,
    const float* __restrict__ A_log, const float* __restrict__ Dvec,
    float* __restrict__ h_out, float* __restrict__ g) {
    const int group = lane >> 4;
    const int sl    = lane & 15;
    const int d     = u * 16 + wave * 4 + group;

    float dt_raw = 0.f, z = 0.f, xr = 0.f;
    f32x4 Bv = {0.f, 0.f, 0.f, 0.f}, Cv = {0.f, 0.f, 0.f, 0.f};
    #pragma unroll
    for (int p = 0; p < NSEG1; ++p) {
        const float* b = pp + p * PP1_STRIDE;
        dt_raw += b[2 * D_INNER + 2 * D_STATE];
        z      += b[d];
        xr     += b[D_INNER + d];
        f32x4 bb = *reinterpret_cast<const f32x4*>(b + 2 * D_INNER + 4 * sl);
        f32x4 cc = *reinterpret_cast<const f32x4*>(b + 2 * D_INNER + D_STATE + 4 * sl);
        Bv += bb; Cv += cc;
    }
    const float dt = (dt_raw > 20.f) ? dt_raw : log1pf(expf(dt_raw));
    const f32x4 Al = *reinterpret_cast<const f32x4*>(A_log + 4 * sl);
    const float x_ssm = xr / (1.f + expf(-xr));

    const f32x4 st = *reinterpret_cast<const f32x4*>(state + (size_t)d * D_STATE + 4 * sl);
    f32x4 h;
    h.x = st.x * expf(-expf(Al.x) * dt) + x_ssm * (dt * Bv.x);
    h.y = st.y * expf(-expf(Al.y) * dt) + x_ssm * (dt * Bv.y);
    h.z = st.z * expf(-expf(Al.z) * dt) + x_ssm * (dt * Bv.z);
    h.w = st.w * expf(-expf(Al.w) * dt) + x_ssm * (dt * Bv.w);
    *reinterpret_cast<f32x4*>(h_out + (size_t)d * D_STATE + 4 * sl) = h;

    float yv = h.x * Cv.x + h.y * Cv.y + h.z * Cv.z + h.w * Cv.w;
    #pragma unroll
    for (int off = 8; off; off >>= 1) yv += __shfl_xor(yv, off, 64);
    if (sl == 0) {
        const float y = yv + Dvec[d] * x_ssm;
        g[d] = y * (z / (1.f + expf(-z)));
    }
}

__device__ __forceinline__ void phase3_body(
    int u, int wave, int lane,
    const float* __restrict__ W_out, const float* __restrict__ g,
    float* __restrict__ op) {
    const int seg  = u & (NSEG3 - 1);
    const int pair = (u >> 3) * 4 + wave;
    const int row0 = pair * 2;
    const int row1 = row0 + 1;
    const int k0 = seg * (D_INNER / NSEG3);
    const float* Wr0 = W_out + (size_t)row0 * D_INNER + k0;
    const float* Wr1 = Wr0 + D_INNER;
    const float* gp  = g + k0;

    float acc0 = 0.f, acc1 = 0.f;
    #pragma unroll
    for (int k = lane * 4; k < D_INNER / NSEG3; k += 64 * 4) {
        f32x4 xv = *reinterpret_cast<const f32x4*>(gp + k);
        f32x4 w0 = *reinterpret_cast<const f32x4*>(Wr0 + k);
        f32x4 w1 = *reinterpret_cast<const f32x4*>(Wr1 + k);
        acc0 += w0.x * xv.x + w0.y * xv.y + w0.z * xv.z + w0.w * xv.w;
        acc1 += w1.x * xv.x + w1.y * xv.y + w1.z * xv.z + w1.w * xv.w;
    }
    #pragma unroll
    for (int off = 32; off; off >>= 1) {
        acc0 += __shfl_down(acc0, off, 64);
        acc1 += __shfl_down(acc1, off, 64);
    }
    if (lane == 0) {
        op[seg * D_MODEL + row0] = acc0;
        op[seg * D_MODEL + row1] = acc1;
    }
}

__device__ __forceinline__ void phase4_body(
    int u, int tid, const float* __restrict__ op, float* __restrict__ out) {
    const int i = u * 256 + tid;
    float s = 0.f;
    #pragma unroll
    for (int p = 0; p < NSEG3; ++p) s += op[p * D_MODEL + i];
    out[i] = s;
}

// ===========================================================================
// Fused cooperative kernel — grid-size agnostic (strides on gridDim.x).
// ===========================================================================
__global__ void __launch_bounds__(256, 4) fused_mamba(
    const float* __restrict__ x, const float* __restrict__ state,
    const float* __restrict__ W_in, const float* __restrict__ A_log,
    const float* __restrict__ Dvec, const float* __restrict__ W_out,
    float* __restrict__ out, float* __restrict__ h_out,
    float* __restrict__ pp, float* __restrict__ g, float* __restrict__ op) {
    cg::grid_group grid = cg::this_grid();
    const int wave = threadIdx.x >> 6;
    const int lane = threadIdx.x & 63;
    const int nb = gridDim.x;

    for (int u = blockIdx.x; u < NU1; u += nb)
        phase1_body(u, wave, lane, W_in, x, pp);
    grid.sync();
    for (int u = blockIdx.x; u < NU2; u += nb)
        phase2_body(u, wave, lane, pp, state, A_log, Dvec, h_out, g);
    grid.sync();
    for (int u = blockIdx.x; u < NU3; u += nb)
        phase3_body(u, wave, lane, W_out, g, op);
    grid.sync();
    for (int u = blockIdx.x; u < NU4; u += nb)
        phase4_body(u, threadIdx.x, op, out);
}

// ===========================================================================
// Fallback kernels (round-3 proven path) — identical arithmetic.
// ===========================================================================
__global__ void __launch_bounds__(256) matvec_in_kernel(
    const float* __restrict__ W, const float* __restrict__ x,
    float* __restrict__ pp) {
    phase1_body(blockIdx.x, threadIdx.x >> 6, threadIdx.x & 63, W, x, pp);
}

__global__ void __launch_bounds__(256) ssm_kernel(
    const float* __restrict__ pp, const float* __restrict__ state,
    const float* __restrict__ A_log, const float* __restrict__ Dvec,
    float* __restrict__ h_out, float* __restrict__ g) {
    phase2_body(blockIdx.x, threadIdx.x >> 6, threadIdx.x & 63, pp, state, A_log, Dvec, h_out, g);
}

__global__ void __launch_bounds__(256) matvec_out_kernel(
    const float* __restrict__ W, const float* __restrict__ g,
    float* __restrict__ op) {
    phase3_body(blockIdx.x, threadIdx.x >> 6, threadIdx.x & 63, W, g, op);
}

__global__ void __launch_bounds__(256) fold_out_kernel(
    const float* __restrict__ op, float* __restrict__ out) {
    phase4_body(blockIdx.x, threadIdx.x, op, out);
}

extern "C" void kernel_launch(void* const* d_in, const int* in_sizes, int n_in,
                              void* d_out, int out_size, void* d_ws, size_t ws_size,
                              hipStream_t stream) {
    const float* x     = (const float*)d_in[0];
    const float* state = (const float*)d_in[1];
    const float* W_in  = (const float*)d_in[2];
    const float* A_log = (const float*)d_in[3];
    const float* Dvec  = (const float*)d_in[4];
    const float* W_out = (const float*)d_in[5];

    float* out   = (float*)d_out;          // [4096]
    float* h_out = out + D_MODEL;          // [8192*64]

    float* pp = (float*)d_ws;              // [4][16516] proj partials
    float* g  = pp + G_OFF;                // [8192]
    float* op = pp + OP_OFF;               // [8][4096] out partials

    void* args[] = {(void*)&x, (void*)&state, (void*)&W_in, (void*)&A_log,
                    (void*)&Dvec, (void*)&W_out, (void*)&out, (void*)&h_out,
                    (void*)&pp, (void*)&g, (void*)&op};

    // Query actual cooperative capacity — never hard-code it.
    int dev = 0;
    (void)hipGetDevice(&dev);
    int cu = 0;
    (void)hipDeviceGetAttribute(&cu, hipDeviceAttributeMultiprocessorCount, dev);
    int maxb = 0;
    (void)hipOccupancyMaxActiveBlocksPerMultiprocessor(&maxb, fused_mamba, 256, 0);

    hipError_t err = hipErrorUnknown;
    long cap = (long)maxb * (long)cu;
    if (cap > 2048) cap = 2048;
    if (cap >= 64) {
        err = hipLaunchCooperativeKernel((const void*)fused_mamba,
                                         dim3((unsigned)cap), dim3(256),
                                         args, 0, stream);
        if (err != hipSuccess && cap > 512) {
            err = hipLaunchCooperativeKernel((const void*)fused_mamba,
                                             dim3(512), dim3(256),
                                             args, 0, stream);
        }
    }
    if (err != hipSuccess) {
        // Proven 4-kernel path (bitwise-identical results).
        matvec_in_kernel<<<2065 * NSEG1, 256, 0, stream>>>(W_in, x, pp);
        ssm_kernel<<<NU2, 256, 0, stream>>>(pp, state, A_log, Dvec, h_out, g);
        matvec_out_kernel<<<512 * NSEG3, 256, 0, stream>>>(W_out, g, op);
        fold_out_kernel<<<NU4, 256, 0, stream>>>(op, out);
    }
}

// Round 6
// 76.889 us; speedup vs baseline: 4.2794x; 4.2794x over previous
//
#include <hip/hip_runtime.h>
#include <math.h>

#define D_MODEL 4096
#define D_INNER 8192
#define D_STATE 64
#define PROJ_OUT (2 * D_INNER + 2 * D_STATE + 1)  // 16513

typedef float f32x4 __attribute__((ext_vector_type(4)));

// ws layout (floats):
#define NSEG1 8
#define PP1_STRIDE 16516                 // PROJ_OUT padded to x4
#define G_OFF (NSEG1 * PP1_STRIDE)       // 132128
#define NSEG3 16

// ---------------------------------------------------------------------------
// Kernel 1: proj partials = W_in @ x, column-split 8 ways.
// Block = 4 waves; wave = one row-pair over a 512-col segment (4 KB/row-pair).
// Small units -> cheap tail drain. W_in nontemporal (single-use, > L3).
// ---------------------------------------------------------------------------
__global__ void __launch_bounds__(256) matvec_in_kernel(
    const float* __restrict__ W, const float* __restrict__ x,
    float* __restrict__ pp) {
    const int wave = threadIdx.x >> 6;
    const int lane = threadIdx.x & 63;
    const int seg  = blockIdx.x & (NSEG1 - 1);
    const int pair = (blockIdx.x >> 3) * 4 + wave;
    const int row0 = pair * 2;
    if (row0 >= PROJ_OUT) return;
    const int row1 = row0 + 1;
    const bool has1 = (row1 < PROJ_OUT);

    const int k0 = seg * (D_MODEL / NSEG1);  // 512-col segment
    const float* Wr0 = W + (size_t)row0 * D_MODEL + k0;
    const float* Wr1 = has1 ? (Wr0 + D_MODEL) : Wr0;
    const float* xp  = x + k0;

    float acc0 = 0.f, acc1 = 0.f;
    #pragma unroll
    for (int k = lane * 4; k < D_MODEL / NSEG1; k += 64 * 4) {
        f32x4 xv = *reinterpret_cast<const f32x4*>(xp + k);
        f32x4 w0 = __builtin_nontemporal_load(reinterpret_cast<const f32x4*>(Wr0 + k));
        f32x4 w1 = __builtin_nontemporal_load(reinterpret_cast<const f32x4*>(Wr1 + k));
        acc0 += w0.x * xv.x + w0.y * xv.y + w0.z * xv.z + w0.w * xv.w;
        acc1 += w1.x * xv.x + w1.y * xv.y + w1.z * xv.z + w1.w * xv.w;
    }
    #pragma unroll
    for (int off = 32; off; off >>= 1) {
        acc0 += __shfl_down(acc0, off, 64);
        acc1 += __shfl_down(acc1, off, 64);
    }
    if (lane == 0) {
        pp[seg * PP1_STRIDE + row0] = acc0;
        if (has1) pp[seg * PP1_STRIDE + row1] = acc1;
    }
}

// ---------------------------------------------------------------------------
// Kernel 2: SSM update + gating; folds the 8 column-partials inline.
// Also zeroes out[0:4096] (blocks 0..15) so kernel 3 can accumulate into it.
// ---------------------------------------------------------------------------
__global__ void __launch_bounds__(256) ssm_kernel(
    const float* __restrict__ pp, const float* __restrict__ state,
    const float* __restrict__ A_log, const float* __restrict__ Dvec,
    float* __restrict__ h_out, float* __restrict__ g, float* __restrict__ out) {
    if (blockIdx.x < D_MODEL / 256)
        out[blockIdx.x * 256 + threadIdx.x] = 0.f;

    const int wave  = threadIdx.x >> 6;
    const int lane  = threadIdx.x & 63;
    const int group = lane >> 4;
    const int sl    = lane & 15;
    const int d     = blockIdx.x * 16 + wave * 4 + group;

    float dt_raw = 0.f, z = 0.f, xr = 0.f;
    f32x4 Bv = {0.f, 0.f, 0.f, 0.f}, Cv = {0.f, 0.f, 0.f, 0.f};
    #pragma unroll
    for (int p = 0; p < NSEG1; ++p) {
        const float* b = pp + p * PP1_STRIDE;
        dt_raw += b[2 * D_INNER + 2 * D_STATE];
        z      += b[d];
        xr     += b[D_INNER + d];
        f32x4 bb = *reinterpret_cast<const f32x4*>(b + 2 * D_INNER + 4 * sl);
        f32x4 cc = *reinterpret_cast<const f32x4*>(b + 2 * D_INNER + D_STATE + 4 * sl);
        Bv += bb; Cv += cc;
    }
    const float dt = (dt_raw > 20.f) ? dt_raw : log1pf(expf(dt_raw));
    const f32x4 Al = *reinterpret_cast<const f32x4*>(A_log + 4 * sl);
    const float x_ssm = xr / (1.f + expf(-xr));

    const f32x4 st = *reinterpret_cast<const f32x4*>(state + (size_t)d * D_STATE + 4 * sl);
    f32x4 h;
    h.x = st.x * expf(-expf(Al.x) * dt) + x_ssm * (dt * Bv.x);
    h.y = st.y * expf(-expf(Al.y) * dt) + x_ssm * (dt * Bv.y);
    h.z = st.z * expf(-expf(Al.z) * dt) + x_ssm * (dt * Bv.z);
    h.w = st.w * expf(-expf(Al.w) * dt) + x_ssm * (dt * Bv.w);
    *reinterpret_cast<f32x4*>(h_out + (size_t)d * D_STATE + 4 * sl) = h;

    float yv = h.x * Cv.x + h.y * Cv.y + h.z * Cv.z + h.w * Cv.w;
    #pragma unroll
    for (int off = 8; off; off >>= 1) yv += __shfl_xor(yv, off, 64);
    if (sl == 0) {
        const float y = yv + Dvec[d] * x_ssm;
        g[d] = y * (z / (1.f + expf(-z)));
    }
}

// ---------------------------------------------------------------------------
// Kernel 3: out += W_out @ g, column-split 16 ways, accumulated via atomicAdd
// (16 adds per output element; out pre-zeroed by kernel 2; stream-ordered).
// ---------------------------------------------------------------------------
__global__ void __launch_bounds__(256) matvec_out_kernel(
    const float* __restrict__ W, const float* __restrict__ g,
    float* __restrict__ out) {
    const int wave = threadIdx.x >> 6;
    const int lane = threadIdx.x & 63;
    const int seg  = blockIdx.x & (NSEG3 - 1);
    const int pair = (blockIdx.x >> 4) * 4 + wave;
    const int row0 = pair * 2;
    const int row1 = row0 + 1;

    const int k0 = seg * (D_INNER / NSEG3);  // 512-col segment
    const float* Wr0 = W + (size_t)row0 * D_INNER + k0;
    const float* Wr1 = Wr0 + D_INNER;
    const float* gp  = g + k0;

    float acc0 = 0.f, acc1 = 0.f;
    #pragma unroll
    for (int k = lane * 4; k < D_INNER / NSEG3; k += 64 * 4) {
        f32x4 xv = *reinterpret_cast<const f32x4*>(gp + k);
        f32x4 w0 = *reinterpret_cast<const f32x4*>(Wr0 + k);
        f32x4 w1 = *reinterpret_cast<const f32x4*>(Wr1 + k);
        acc0 += w0.x * xv.x + w0.y * xv.y + w0.z * xv.z + w0.w * xv.w;
        acc1 += w1.x * xv.x + w1.y * xv.y + w1.z * xv.z + w1.w * xv.w;
    }
    #pragma unroll
    for (int off = 32; off; off >>= 1) {
        acc0 += __shfl_down(acc0, off, 64);
        acc1 += __shfl_down(acc1, off, 64);
    }
    if (lane == 0) {
        atomicAdd(&out[row0], acc0);
        atomicAdd(&out[row1], acc1);
    }
}

extern "C" void kernel_launch(void* const* d_in, const int* in_sizes, int n_in,
                              void* d_out, int out_size, void* d_ws, size_t ws_size,
                              hipStream_t stream) {
    const float* x     = (const float*)d_in[0];
    const float* state = (const float*)d_in[1];
    const float* W_in  = (const float*)d_in[2];
    const float* A_log = (const float*)d_in[3];
    const float* Dvec  = (const float*)d_in[4];
    const float* W_out = (const float*)d_in[5];

    float* out   = (float*)d_out;          // [4096]
    float* h_out = out + D_MODEL;          // [8192*64]

    float* pp = (float*)d_ws;              // [8][16516] proj partials
    float* g  = pp + G_OFF;                // [8192]

    // k1: 2065 pair-groups x 8 segs = 16520 blocks (covers 8257 row-pairs)
    matvec_in_kernel<<<2065 * NSEG1, 256, 0, stream>>>(W_in, x, pp);
    // k2: 512 blocks (16 d-rows each); also zeroes out[]
    ssm_kernel<<<D_INNER / 16, 256, 0, stream>>>(pp, state, A_log, Dvec, h_out, g, out);
    // k3: 512 pair-groups x 16 segs = 8192 blocks, atomic accumulate into out
    matvec_out_kernel<<<512 * NSEG3, 256, 0, stream>>>(W_out, g, out);
}

// Round 7
// 71.441 us; speedup vs baseline: 4.6058x; 1.0763x over previous
//
#include <hip/hip_runtime.h>
#include <math.h>

#define D_MODEL 4096
#define D_INNER 8192
#define D_STATE 64
#define PROJ_OUT (2 * D_INNER + 2 * D_STATE + 1)  // 16513

typedef float f32x4 __attribute__((ext_vector_type(4)));

// ws layout (floats):
#define NSEG1 4
#define PP1_STRIDE 16516                 // PROJ_OUT padded to x4
#define G_OFF (NSEG1 * PP1_STRIDE)       // 66064
#define NSEG3 8

// ---------------------------------------------------------------------------
// Kernel 1: proj partials = W_in @ x, column-split 4 ways (1024-col segments,
// 4-iter k-loop — round-3 proven optimum). Block = 4 waves = 4 row-pairs,
// same segment. W_in nontemporal (single-use, > L3; preserve L3 for W_out).
// ---------------------------------------------------------------------------
__global__ void __launch_bounds__(256) matvec_in_kernel(
    const float* __restrict__ W, const float* __restrict__ x,
    float* __restrict__ pp) {
    const int wave = threadIdx.x >> 6;
    const int lane = threadIdx.x & 63;
    const int seg  = blockIdx.x & (NSEG1 - 1);
    const int pair = (blockIdx.x >> 2) * 4 + wave;
    const int row0 = pair * 2;
    if (row0 >= PROJ_OUT) return;
    const int row1 = row0 + 1;
    const bool has1 = (row1 < PROJ_OUT);

    const int k0 = seg * (D_MODEL / NSEG1);  // 1024-col segment
    const float* Wr0 = W + (size_t)row0 * D_MODEL + k0;
    const float* Wr1 = has1 ? (Wr0 + D_MODEL) : Wr0;
    const float* xp  = x + k0;

    float acc0 = 0.f, acc1 = 0.f;
    #pragma unroll
    for (int k = lane * 4; k < D_MODEL / NSEG1; k += 64 * 4) {
        f32x4 xv = *reinterpret_cast<const f32x4*>(xp + k);
        f32x4 w0 = __builtin_nontemporal_load(reinterpret_cast<const f32x4*>(Wr0 + k));
        f32x4 w1 = __builtin_nontemporal_load(reinterpret_cast<const f32x4*>(Wr1 + k));
        acc0 += w0.x * xv.x + w0.y * xv.y + w0.z * xv.z + w0.w * xv.w;
        acc1 += w1.x * xv.x + w1.y * xv.y + w1.z * xv.z + w1.w * xv.w;
    }
    #pragma unroll
    for (int off = 32; off; off >>= 1) {
        acc0 += __shfl_down(acc0, off, 64);
        acc1 += __shfl_down(acc1, off, 64);
    }
    if (lane == 0) {
        pp[seg * PP1_STRIDE + row0] = acc0;
        if (has1) pp[seg * PP1_STRIDE + row1] = acc1;
    }
}

// ---------------------------------------------------------------------------
// Kernel 2: SSM update + gating; folds the 4 column-partials inline.
// Blocks 0..15 also zero out[0:4096] so kernel 3 can atomically accumulate.
// ---------------------------------------------------------------------------
__global__ void __launch_bounds__(256) ssm_kernel(
    const float* __restrict__ pp, const float* __restrict__ state,
    const float* __restrict__ A_log, const float* __restrict__ Dvec,
    float* __restrict__ h_out, float* __restrict__ g, float* __restrict__ out) {
    if (blockIdx.x < D_MODEL / 256)
        out[blockIdx.x * 256 + threadIdx.x] = 0.f;

    const int wave  = threadIdx.x >> 6;
    const int lane  = threadIdx.x & 63;
    const int group = lane >> 4;
    const int sl    = lane & 15;
    const int d     = blockIdx.x * 16 + wave * 4 + group;

    float dt_raw = 0.f, z = 0.f, xr = 0.f;
    f32x4 Bv = {0.f, 0.f, 0.f, 0.f}, Cv = {0.f, 0.f, 0.f, 0.f};
    #pragma unroll
    for (int p = 0; p < NSEG1; ++p) {
        const float* b = pp + p * PP1_STRIDE;
        dt_raw += b[2 * D_INNER + 2 * D_STATE];
        z      += b[d];
        xr     += b[D_INNER + d];
        f32x4 bb = *reinterpret_cast<const f32x4*>(b + 2 * D_INNER + 4 * sl);
        f32x4 cc = *reinterpret_cast<const f32x4*>(b + 2 * D_INNER + D_STATE + 4 * sl);
        Bv += bb; Cv += cc;
    }
    const float dt = (dt_raw > 20.f) ? dt_raw : log1pf(expf(dt_raw));
    const f32x4 Al = *reinterpret_cast<const f32x4*>(A_log + 4 * sl);
    const float x_ssm = xr / (1.f + expf(-xr));

    const f32x4 st = *reinterpret_cast<const f32x4*>(state + (size_t)d * D_STATE + 4 * sl);
    f32x4 h;
    h.x = st.x * expf(-expf(Al.x) * dt) + x_ssm * (dt * Bv.x);
    h.y = st.y * expf(-expf(Al.y) * dt) + x_ssm * (dt * Bv.y);
    h.z = st.z * expf(-expf(Al.z) * dt) + x_ssm * (dt * Bv.z);
    h.w = st.w * expf(-expf(Al.w) * dt) + x_ssm * (dt * Bv.w);
    *reinterpret_cast<f32x4*>(h_out + (size_t)d * D_STATE + 4 * sl) = h;

    float yv = h.x * Cv.x + h.y * Cv.y + h.z * Cv.z + h.w * Cv.w;
    #pragma unroll
    for (int off = 8; off; off >>= 1) yv += __shfl_xor(yv, off, 64);
    if (sl == 0) {
        const float y = yv + Dvec[d] * x_ssm;
        g[d] = y * (z / (1.f + expf(-z)));
    }
}

// ---------------------------------------------------------------------------
// Kernel 3: out += W_out @ g, column-split 8 ways (1024-col segments),
// accumulated via atomicAdd (8 adds/output; out pre-zeroed by kernel 2).
// Normal (cached) loads: W_out is L3-resident across graph replays.
// ---------------------------------------------------------------------------
__global__ void __launch_bounds__(256) matvec_out_kernel(
    const float* __restrict__ W, const float* __restrict__ g,
    float* __restrict__ out) {
    const int wave = threadIdx.x >> 6;
    const int lane = threadIdx.x & 63;
    const int seg  = blockIdx.x & (NSEG3 - 1);
    const int pair = (blockIdx.x >> 3) * 4 + wave;
    const int row0 = pair * 2;
    const int row1 = row0 + 1;

    const int k0 = seg * (D_INNER / NSEG3);  // 1024-col segment
    const float* Wr0 = W + (size_t)row0 * D_INNER + k0;
    const float* Wr1 = Wr0 + D_INNER;
    const float* gp  = g + k0;

    float acc0 = 0.f, acc1 = 0.f;
    #pragma unroll
    for (int k = lane * 4; k < D_INNER / NSEG3; k += 64 * 4) {
        f32x4 xv = *reinterpret_cast<const f32x4*>(gp + k);
        f32x4 w0 = *reinterpret_cast<const f32x4*>(Wr0 + k);
        f32x4 w1 = *reinterpret_cast<const f32x4*>(Wr1 + k);
        acc0 += w0.x * xv.x + w0.y * xv.y + w0.z * xv.z + w0.w * xv.w;
        acc1 += w1.x * xv.x + w1.y * xv.y + w1.z * xv.z + w1.w * xv.w;
    }
    #pragma unroll
    for (int off = 32; off; off >>= 1) {
        acc0 += __shfl_down(acc0, off, 64);
        acc1 += __shfl_down(acc1, off, 64);
    }
    if (lane == 0) {
        atomicAdd(&out[row0], acc0);
        atomicAdd(&out[row1], acc1);
    }
}

extern "C" void kernel_launch(void* const* d_in, const int* in_sizes, int n_in,
                              void* d_out, int out_size, void* d_ws, size_t ws_size,
                              hipStream_t stream) {
    const float* x     = (const float*)d_in[0];
    const float* state = (const float*)d_in[1];
    const float* W_in  = (const float*)d_in[2];
    const float* A_log = (const float*)d_in[3];
    const float* Dvec  = (const float*)d_in[4];
    const float* W_out = (const float*)d_in[5];

    float* out   = (float*)d_out;          // [4096]
    float* h_out = out + D_MODEL;          // [8192*64]

    float* pp = (float*)d_ws;              // [4][16516] proj partials
    float* g  = pp + G_OFF;                // [8192]

    // k1: 2065 pair-groups x 4 segs = 8260 blocks (covers 8257 row-pairs)
    matvec_in_kernel<<<2065 * NSEG1, 256, 0, stream>>>(W_in, x, pp);
    // k2: 512 blocks (16 d-rows each); also zeroes out[]
    ssm_kernel<<<D_INNER / 16, 256, 0, stream>>>(pp, state, A_log, Dvec, h_out, g, out);
    // k3: 512 pair-groups x 8 segs = 4096 blocks, atomic accumulate into out
    matvec_out_kernel<<<512 * NSEG3, 256, 0, stream>>>(W_out, g, out);
}